// Round 1
// baseline (642.527 us; speedup 1.0000x reference)
//
#include <hip/hip_runtime.h>
#include <hip/hip_bf16.h>
#include <math.h>

// Problem constants
#define BB 4
#define TT 2048
#define CC 1024
#define HH 16
#define DD 64
#define WW 256
#define MM (BB*TT)   // 8192 rows

typedef __bf16 bf16x8 __attribute__((ext_vector_type(8)));
typedef float  f32x4  __attribute__((ext_vector_type(4)));

// ---------------------------------------------------------------------------
// async global->LDS 16B copy: LDS dest is wave-uniform base + lane*16
// ---------------------------------------------------------------------------
__device__ __forceinline__ void async_cp16(const void* g, void* l) {
  __builtin_amdgcn_global_load_lds(
      (const __attribute__((address_space(1))) void*)g,
      (__attribute__((address_space(3))) void*)l,
      16, 0, 0);
}

// ---------------------------------------------------------------------------
// fp32 -> bf16 conversion (4 elems/thread)
// ---------------------------------------------------------------------------
__global__ void f32_to_bf16(const float* __restrict__ in,
                            __hip_bfloat16* __restrict__ out, int n) {
  int i = (blockIdx.x * 256 + threadIdx.x) * 4;
  if (i + 3 < n) {
    float4 v = *(const float4*)(in + i);
    out[i + 0] = __float2bfloat16(v.x);
    out[i + 1] = __float2bfloat16(v.y);
    out[i + 2] = __float2bfloat16(v.z);
    out[i + 3] = __float2bfloat16(v.w);
  }
}

// ---------------------------------------------------------------------------
// GEMM: C[M,N] = A[M,K] * W[N,K]^T   (both A and W row-major, K inner)
// bf16 inputs, fp32 accumulate. 128x128 block tile, BK=64, 4 waves (2x2),
// each wave 64x64 via 4x4 MFMA 16x16x32 tiles.
// LDS layout: [kchunk (8B of k)][row][16B] -- contiguous for global_load_lds,
// 2-way max bank aliasing on ds_read_b128 fragment loads.
// ---------------------------------------------------------------------------
template<bool OUT_BF16>
__global__ __launch_bounds__(256, 2)
void gemm_bt(const unsigned short* __restrict__ A,
             const unsigned short* __restrict__ Bw,
             void* __restrict__ Co, int M, int N, int K) {
  __shared__ __align__(16) unsigned short As[8 * 1024]; // 16 KB
  __shared__ __align__(16) unsigned short Bs[8 * 1024]; // 16 KB

  const int tid  = threadIdx.x;
  const int w    = tid >> 6;
  const int lane = tid & 63;
  const int quad = lane >> 4;
  const int l15  = lane & 15;
  const int m0 = blockIdx.x * 128;
  const int n0 = blockIdx.y * 128;
  const int wm = w & 1;        // 2x2 wave grid
  const int wn = w >> 1;

  f32x4 acc[4][4];
#pragma unroll
  for (int i = 0; i < 4; i++)
#pragma unroll
    for (int j = 0; j < 4; j++) acc[i][j] = (f32x4)0.0f;

  for (int k0 = 0; k0 < K; k0 += 64) {
    // stage A,B tiles: 16 wave-calls each (4 per wave); idx -> (kc, mhalf)
#pragma unroll
    for (int i = 0; i < 4; i++) {
      int idx = w + 4 * i;        // 0..15
      int kc  = idx >> 1;         // 0..7  (which 8-element k chunk)
      int mh  = idx & 1;          // 0..1  (which 64-row half)
      const unsigned short* ga =
          A + (size_t)(m0 + mh * 64 + lane) * K + (k0 + kc * 8);
      async_cp16(ga, &As[kc * 1024 + mh * 512]);
      const unsigned short* gb =
          Bw + (size_t)(n0 + mh * 64 + lane) * K + (k0 + kc * 8);
      async_cp16(gb, &Bs[kc * 1024 + mh * 512]);
    }
    __syncthreads();

#pragma unroll
    for (int ks = 0; ks < 2; ks++) {
      bf16x8 af[4], bfv[4];
      int kc = ks * 4 + quad;
#pragma unroll
      for (int t = 0; t < 4; t++) {
        af[t]  = *(const bf16x8*)&As[kc * 1024 + (wm * 64 + t * 16 + l15) * 8];
        bfv[t] = *(const bf16x8*)&Bs[kc * 1024 + (wn * 64 + t * 16 + l15) * 8];
      }
#pragma unroll
      for (int tm = 0; tm < 4; tm++)
#pragma unroll
        for (int tn = 0; tn < 4; tn++)
          acc[tm][tn] = __builtin_amdgcn_mfma_f32_16x16x32_bf16(
              af[tm], bfv[tn], acc[tm][tn], 0, 0, 0);
    }
    __syncthreads();
  }

  // epilogue: C/D layout col=lane&15, row=quad*4+r
#pragma unroll
  for (int tm = 0; tm < 4; tm++)
#pragma unroll
    for (int tn = 0; tn < 4; tn++)
#pragma unroll
      for (int r = 0; r < 4; r++) {
        int row = m0 + wm * 64 + tm * 16 + quad * 4 + r;
        int col = n0 + wn * 64 + tn * 16 + l15;
        float v = acc[tm][tn][r];
        if (OUT_BF16)
          ((__hip_bfloat16*)Co)[(size_t)row * N + col] = __float2bfloat16(v);
        else
          ((float*)Co)[(size_t)row * N + col] = v;
      }
}

// ---------------------------------------------------------------------------
// Sliding-window flash attention (VALU, correctness-first).
// qkv: bf16 [B*T, 3C], cols [0,C)=Q, [C,2C)=K, [2C,3C)=V, head slice h*64+d.
// One block per (q-tile of 64, head, batch); 4 waves, 16 queries per wave.
// Key chunks of 64 staged in LDS; online softmax; PV via v_readlane.
// ---------------------------------------------------------------------------
__global__ __launch_bounds__(256, 2)
void attn_win(const __hip_bfloat16* __restrict__ qkv,
              __hip_bfloat16* __restrict__ y) {
  __shared__ __align__(16) float Qs[64 * 64];  // scaled Q, broadcast-read only
  __shared__ __align__(16) float Ks[64 * 68];  // pad 68: aligned float4, 2-way banks
  __shared__ float Vs[64 * 65];                // pad 65: scalar reads, 2-way banks

  const int tid  = threadIdx.x;
  const int w    = tid >> 6;
  const int lane = tid & 63;
  const int q0 = blockIdx.x * 64;
  const int h  = blockIdx.y;
  const int b  = blockIdx.z;
  const size_t base = (size_t)b * TT;
  const int S3 = 3 * CC;

  // stage Q (pre-scaled by 1/sqrt(64))
  for (int idx = tid; idx < 64 * 64; idx += 256) {
    int r = idx >> 6, d = idx & 63;
    Qs[r * 64 + d] =
        0.125f * __bfloat162float(qkv[(base + q0 + r) * S3 + h * 64 + d]);
  }

  float mi[16], li[16], ai[16];
#pragma unroll
  for (int i = 0; i < 16; i++) { mi[i] = -INFINITY; li[i] = 0.f; ai[i] = 0.f; }
  const int wq = w * 16;

  for (int c = 0; c < 5; c++) {
    int sc = q0 - 256 + c * 64;   // chunk start (multiple of 64)
    if (sc < 0) continue;         // fully out of range (uniform per block)
    __syncthreads();              // prior chunk's reads done before restage
    for (int idx = tid; idx < 64 * 64; idx += 256) {
      int r = idx >> 6, d = idx & 63;
      Ks[r * 68 + d] =
          __bfloat162float(qkv[(base + sc + r) * S3 + CC + h * 64 + d]);
      Vs[r * 65 + d] =
          __bfloat162float(qkv[(base + sc + r) * S3 + 2 * CC + h * 64 + d]);
    }
    __syncthreads();

    // ---- QK^T: lane = key j, 16 queries per wave
    float dot[16];
#pragma unroll
    for (int i = 0; i < 16; i++) dot[i] = 0.f;
    for (int d4 = 0; d4 < 16; d4++) {
      f32x4 kv = *(const f32x4*)&Ks[lane * 68 + d4 * 4];
#pragma unroll
      for (int i = 0; i < 16; i++) {
        f32x4 qv = *(const f32x4*)&Qs[(wq + i) * 64 + d4 * 4];
        dot[i] += kv[0]*qv[0] + kv[1]*qv[1] + kv[2]*qv[2] + kv[3]*qv[3];
      }
    }

    // ---- online softmax per query
    int kj = sc + lane;
    float pj[16], alpha[16];
#pragma unroll
    for (int i = 0; i < 16; i++) {
      int qi = q0 + wq + i;
      float sv = (kj <= qi && kj >= qi - (WW - 1)) ? dot[i] : -INFINITY;
      float cm = sv;
      for (int off = 32; off; off >>= 1) cm = fmaxf(cm, __shfl_xor(cm, off, 64));
      float mn = fmaxf(mi[i], cm);
      float a_, p_;
      if (mn == -INFINITY) { a_ = 1.f; p_ = 0.f; }   // fully-masked chunk
      else {
        a_ = __expf(mi[i] - mn);   // mi=-inf -> 0, correct
        p_ = __expf(sv - mn);      // sv=-inf -> 0, correct
        mi[i] = mn;
      }
      float ps = p_;
      for (int off = 32; off; off >>= 1) ps += __shfl_xor(ps, off, 64);
      li[i] = li[i] * a_ + ps;
      alpha[i] = a_;
      pj[i] = p_;
    }

    // ---- PV: lane = d; p broadcast via readlane (wave-uniform j)
#pragma unroll
    for (int i = 0; i < 16; i++) ai[i] *= alpha[i];
    for (int j = 0; j < 64; j++) {
      float vv = Vs[j * 65 + lane];
#pragma unroll
      for (int i = 0; i < 16; i++) {
        float pb = __uint_as_float(
            __builtin_amdgcn_readlane(__float_as_uint(pj[i]), j));
        ai[i] = fmaf(pb, vv, ai[i]);
      }
    }
  }

#pragma unroll
  for (int i = 0; i < 16; i++) {
    y[(base + q0 + wq + i) * CC + h * 64 + lane] =
        __float2bfloat16(ai[i] / li[i]);
  }
}

// ---------------------------------------------------------------------------
extern "C" void kernel_launch(void* const* d_in, const int* in_sizes, int n_in,
                              void* d_out, int out_size, void* d_ws, size_t ws_size,
                              hipStream_t stream) {
  const float* x     = (const float*)d_in[0];
  const float* wqkv  = (const float*)d_in[1];
  const float* wproj = (const float*)d_in[2];
  float* out = (float*)d_out;

  char* ws = (char*)d_ws;
  // workspace layout (bytes):
  //   [0,16M)   x bf16        [16M,22M) Wqkv bf16   [22M,24M) Wproj bf16
  //   [24M,72M) qkv bf16      [72M,88M) y bf16
  unsigned short* xb     = (unsigned short*)(ws);
  unsigned short* wqkvb  = (unsigned short*)(ws + (size_t)16 * 1024 * 1024);
  unsigned short* wprojb = (unsigned short*)(ws + (size_t)22 * 1024 * 1024);
  unsigned short* qkvb   = (unsigned short*)(ws + (size_t)24 * 1024 * 1024);
  unsigned short* yb     = (unsigned short*)(ws + (size_t)72 * 1024 * 1024);

  const int nx = MM * CC;        // 8388608
  const int nq = 3 * CC * CC;    // 3145728
  const int np = CC * CC;        // 1048576

  f32_to_bf16<<<nx / 1024, 256, 0, stream>>>(x,     (__hip_bfloat16*)xb,     nx);
  f32_to_bf16<<<nq / 1024, 256, 0, stream>>>(wqkv,  (__hip_bfloat16*)wqkvb,  nq);
  f32_to_bf16<<<np / 1024, 256, 0, stream>>>(wproj, (__hip_bfloat16*)wprojb, np);

  // qkv = x @ Wqkv^T : [8192,1024] x [3072,1024]^T -> [8192,3072] bf16
  gemm_bt<true><<<dim3(MM / 128, (3 * CC) / 128), 256, 0, stream>>>(
      xb, wqkvb, (void*)qkvb, MM, 3 * CC, CC);

  // attention -> y bf16 [8192,1024]
  attn_win<<<dim3(TT / 64, HH, BB), 256, 0, stream>>>(
      (const __hip_bfloat16*)qkvb, (__hip_bfloat16*)yb);

  // out = y @ Wproj^T : [8192,1024] x [1024,1024]^T -> fp32 d_out
  gemm_bt<false><<<dim3(MM / 128, CC / 128), 256, 0, stream>>>(
      yb, wprojb, (void*)out, MM, CC, CC);
}

// Round 2
// 295.072 us; speedup vs baseline: 2.1775x; 2.1775x over previous
//
#include <hip/hip_runtime.h>
#include <hip/hip_bf16.h>
#include <math.h>

// Problem constants
#define BB 4
#define TT 2048
#define CC 1024
#define HH 16
#define DD 64
#define WW 256
#define MM (BB*TT)   // 8192 rows

typedef __bf16 bf16x8 __attribute__((ext_vector_type(8)));
typedef __bf16 bf16x4 __attribute__((ext_vector_type(4)));
typedef float  f32x4  __attribute__((ext_vector_type(4)));

// async global->LDS 16B: LDS dest is wave-uniform base; HW adds lane*16
__device__ __forceinline__ void async_cp16(const void* g, void* l) {
  __builtin_amdgcn_global_load_lds(
      (const __attribute__((address_space(1))) void*)g,
      (__attribute__((address_space(3))) void*)l, 16, 0, 0);
}

__device__ __forceinline__ unsigned short f2bf(float v) {
  __hip_bfloat16 h = __float2bfloat16(v);
  return *(unsigned short*)&h;
}

// ---------------------------------------------------------------------------
// fp32 -> bf16 conversion
// ---------------------------------------------------------------------------
__global__ void f32_to_bf16(const float* __restrict__ in,
                            __hip_bfloat16* __restrict__ out, int n) {
  int i = (blockIdx.x * 256 + threadIdx.x) * 4;
  if (i + 3 < n) {
    float4 v = *(const float4*)(in + i);
    out[i + 0] = __float2bfloat16(v.x);
    out[i + 1] = __float2bfloat16(v.y);
    out[i + 2] = __float2bfloat16(v.z);
    out[i + 3] = __float2bfloat16(v.w);
  }
}

// ---------------------------------------------------------------------------
// GEMM: C = A[M,K] * W[N,K]^T, bf16 in, fp32 acc. 128x128 tile, BK=64.
// MODE 0: fp32 output row-major.
// MODE 1: qkv scatter -> Qh/Kh/Vh [b*h][t][d] bf16, Q pre-scaled by 0.125.
// ---------------------------------------------------------------------------
template<int MODE>
__global__ __launch_bounds__(256, 2)
void gemm_bt(const unsigned short* __restrict__ A,
             const unsigned short* __restrict__ Bw,
             void* __restrict__ Co, int M, int N, int K,
             unsigned short* __restrict__ Qh,
             unsigned short* __restrict__ Kh,
             unsigned short* __restrict__ Vh) {
  __shared__ __align__(16) unsigned short As[8 * 1024]; // [kc][128 rows][8]
  __shared__ __align__(16) unsigned short Bs[8 * 1024];

  const int tid  = threadIdx.x;
  const int w    = tid >> 6;
  const int lane = tid & 63;
  const int quad = lane >> 4;
  const int l15  = lane & 15;
  const int m0 = blockIdx.x * 128;
  const int n0 = blockIdx.y * 128;
  const int wm = w & 1;
  const int wn = w >> 1;

  f32x4 acc[4][4];
#pragma unroll
  for (int i = 0; i < 4; i++)
#pragma unroll
    for (int j = 0; j < 4; j++) acc[i][j] = (f32x4)0.0f;

  for (int k0 = 0; k0 < K; k0 += 64) {
#pragma unroll
    for (int i = 0; i < 4; i++) {
      int idx = w + 4 * i;
      int kc  = idx >> 1;
      int mh  = idx & 1;
      const unsigned short* ga =
          A + (size_t)(m0 + mh * 64 + lane) * K + (k0 + kc * 8);
      async_cp16(ga, &As[kc * 1024 + mh * 512]);
      const unsigned short* gb =
          Bw + (size_t)(n0 + mh * 64 + lane) * K + (k0 + kc * 8);
      async_cp16(gb, &Bs[kc * 1024 + mh * 512]);
    }
    __syncthreads();

#pragma unroll
    for (int ks = 0; ks < 2; ks++) {
      bf16x8 af[4], bfv[4];
      int kc = ks * 4 + quad;
#pragma unroll
      for (int t = 0; t < 4; t++) {
        af[t]  = *(const bf16x8*)&As[kc * 1024 + (wm * 64 + t * 16 + l15) * 8];
        bfv[t] = *(const bf16x8*)&Bs[kc * 1024 + (wn * 64 + t * 16 + l15) * 8];
      }
#pragma unroll
      for (int tm = 0; tm < 4; tm++)
#pragma unroll
        for (int tn = 0; tn < 4; tn++)
          acc[tm][tn] = __builtin_amdgcn_mfma_f32_16x16x32_bf16(
              af[tm], bfv[tn], acc[tm][tn], 0, 0, 0);
    }
    __syncthreads();
  }

  if (MODE == 0) {
#pragma unroll
    for (int tm = 0; tm < 4; tm++)
#pragma unroll
      for (int tn = 0; tn < 4; tn++)
#pragma unroll
        for (int r = 0; r < 4; r++) {
          int row = m0 + wm * 64 + tm * 16 + quad * 4 + r;
          int col = n0 + wn * 64 + tn * 16 + l15;
          ((float*)Co)[(size_t)row * N + col] = acc[tm][tn][r];
        }
  } else {
    // scatter qkv: col -> (which, head, d); row -> (b, t)
#pragma unroll
    for (int tm = 0; tm < 4; tm++)
#pragma unroll
      for (int tn = 0; tn < 4; tn++) {
        int colb = n0 + wn * 64 + tn * 16;     // 16-aligned: t3,h uniform
        int t3 = colb >> 10;
        int hh = (colb >> 6) & 15;
        int dd = (colb & 63) + l15;
        unsigned short* dst = (t3 == 0) ? Qh : ((t3 == 1) ? Kh : Vh);
        float sc = (t3 == 0) ? 0.125f : 1.0f;  // 1/sqrt(64), exact
#pragma unroll
        for (int r = 0; r < 4; r++) {
          int row = m0 + wm * 64 + tm * 16 + quad * 4 + r;
          int b = row >> 11, tt = row & 2047;
          dst[((size_t)((b * 16 + hh) * 2048 + tt)) * 64 + dd] =
              f2bf(acc[tm][tn][r] * sc);
        }
      }
  }
}

// ---------------------------------------------------------------------------
// Vh [bh][t][d] -> Vt chunk-blocked [bh][tc=32][d=64][tin=64]
// ---------------------------------------------------------------------------
__global__ __launch_bounds__(256)
void transpose_v(const unsigned short* __restrict__ Vh,
                 unsigned short* __restrict__ Vt) {
  __shared__ __align__(16) unsigned short tile[64 * 72]; // row stride 144B
  const int tid = threadIdx.x;
  const int tc = blockIdx.x, bh = blockIdx.y;
  const unsigned short* src = Vh + ((size_t)bh * 2048 + (size_t)tc * 64) * 64;
  for (int i = tid; i < 512; i += 256) {
    int r = i >> 3, ds = (i & 7) * 8;
    *(uint4*)&tile[r * 72 + ds] = *(const uint4*)&src[(size_t)r * 64 + ds];
  }
  __syncthreads();
  unsigned short* dst = Vt + (size_t)(bh * 32 + tc) * 4096;
  for (int i = tid; i < 512; i += 256) {
    int d = i >> 3, ts = (i & 7) * 8;
    unsigned int w0 = tile[(ts + 0) * 72 + d] | ((unsigned int)tile[(ts + 1) * 72 + d] << 16);
    unsigned int w1 = tile[(ts + 2) * 72 + d] | ((unsigned int)tile[(ts + 3) * 72 + d] << 16);
    unsigned int w2 = tile[(ts + 4) * 72 + d] | ((unsigned int)tile[(ts + 5) * 72 + d] << 16);
    unsigned int w3 = tile[(ts + 6) * 72 + d] | ((unsigned int)tile[(ts + 7) * 72 + d] << 16);
    uint4 o; o.x = w0; o.y = w1; o.z = w2; o.w = w3;
    *(uint4*)&dst[(size_t)d * 64 + ts] = o;
  }
}

// ---------------------------------------------------------------------------
// MFMA sliding-window flash attention.
// Block: 64 queries x 1 (b,h). 4 waves; wave w owns 16-query strip.
// Q pre-scaled. S=QK^T via mfma (C-layout), online softmax, P->LDS,
// O += P*V via mfma with Vt (j-inner) B-frags.
// ---------------------------------------------------------------------------
__global__ __launch_bounds__(256, 2)
void attn_mfma(const unsigned short* __restrict__ Qh,
               const unsigned short* __restrict__ Kh,
               const unsigned short* __restrict__ Vt,
               __hip_bfloat16* __restrict__ y) {
  __shared__ __align__(16) unsigned short Qs[8 * 512]; // [kc_d][q 64][8]
  __shared__ __align__(16) unsigned short Ks[8 * 512]; // [kc_d][j 64][8]
  __shared__ __align__(16) unsigned short Vs[8 * 512]; // [kc_j][d 64][8]
  __shared__ __align__(16) unsigned short Ps[64 * 68]; // [q][j], row 136B

  const int tid  = threadIdx.x;
  const int w    = tid >> 6;
  const int lane = tid & 63;
  const int quad = lane >> 4;
  const int l15  = lane & 15;
  const int q0 = blockIdx.x * 64;
  const int bh = blockIdx.y;            // b*16+h

  const unsigned short* Qg = Qh + ((size_t)bh * 2048 + q0) * 64;

  // stage Q once (visible after first chunk's __syncthreads)
#pragma unroll
  for (int i = 0; i < 2; i++) {
    int kc = w * 2 + i;
    async_cp16(Qg + (size_t)lane * 64 + kc * 8, &Qs[kc * 512]);
  }

  f32x4 Oacc[4];
  float m_[4], l_[4];
#pragma unroll
  for (int t = 0; t < 4; t++) { Oacc[t] = (f32x4)0.0f; }
#pragma unroll
  for (int r = 0; r < 4; r++) { m_[r] = -__builtin_inff(); l_[r] = 0.0f; }

  for (int c = 0; c < 5; c++) {
    const int sc = q0 - 256 + c * 64;   // block-uniform
    if (sc < 0) continue;
    __syncthreads();                    // prior chunk's Ks/Vs reads complete
    const unsigned short* Kg = Kh + ((size_t)bh * 2048 + sc) * 64;
    const unsigned short* Vg = Vt + ((size_t)(bh * 32) + (sc >> 6)) * 4096;
#pragma unroll
    for (int i = 0; i < 2; i++) {
      int kc = w * 2 + i;
      async_cp16(Kg + (size_t)lane * 64 + kc * 8, &Ks[kc * 512]);
      async_cp16(Vg + (size_t)lane * 64 + kc * 8, &Vs[kc * 512]);
    }
    __syncthreads();                    // drains vmcnt -> staging visible

    // ---- S = Q K^T (wave strip w: rows w*16..+16, cols 0..64)
    f32x4 S[4];
#pragma unroll
    for (int tn = 0; tn < 4; tn++) S[tn] = (f32x4)0.0f;
#pragma unroll
    for (int ks = 0; ks < 2; ks++) {
      int kc = ks * 4 + quad;
      bf16x8 aq = *(const bf16x8*)&Qs[kc * 512 + (w * 16 + l15) * 8];
#pragma unroll
      for (int tn = 0; tn < 4; tn++) {
        bf16x8 bk = *(const bf16x8*)&Ks[kc * 512 + (tn * 16 + l15) * 8];
        S[tn] = __builtin_amdgcn_mfma_f32_16x16x32_bf16(aq, bk, S[tn], 0, 0, 0);
      }
    }

    // ---- mask (only first/last chunk partial)
    const int qb = q0 + w * 16 + quad * 4;  // + r
    if (c == 0) {
#pragma unroll
      for (int tn = 0; tn < 4; tn++) {
        int j = sc + tn * 16 + l15;
#pragma unroll
        for (int r = 0; r < 4; r++)
          if (qb + r > j + (WW - 1)) S[tn][r] = -__builtin_inff();
      }
    } else if (sc == q0) {
#pragma unroll
      for (int tn = 0; tn < 4; tn++) {
        int j = sc + tn * 16 + l15;
#pragma unroll
        for (int r = 0; r < 4; r++)
          if (j > qb + r) S[tn][r] = -__builtin_inff();
      }
    }

    // ---- online softmax (row stats across 64 cols: 4 tn regs + 16 lanes)
    float mx[4], al[4], em[4], ps[4];
#pragma unroll
    for (int r = 0; r < 4; r++)
      mx[r] = fmaxf(fmaxf(S[0][r], S[1][r]), fmaxf(S[2][r], S[3][r]));
#pragma unroll
    for (int off = 1; off < 16; off <<= 1)
#pragma unroll
      for (int r = 0; r < 4; r++) mx[r] = fmaxf(mx[r], __shfl_xor(mx[r], off));
#pragma unroll
    for (int r = 0; r < 4; r++) {
      float mn = fmaxf(m_[r], mx[r]);
      em[r] = (mn == -__builtin_inff()) ? 0.0f : mn;
      al[r] = __expf(m_[r] - em[r]);    // m_=-inf -> 0
      m_[r] = mn;
    }
#pragma unroll
    for (int tn = 0; tn < 4; tn++)
#pragma unroll
      for (int r = 0; r < 4; r++)
        S[tn][r] = __expf(S[tn][r] - em[r]);  // masked -inf -> 0
#pragma unroll
    for (int r = 0; r < 4; r++)
      ps[r] = (S[0][r] + S[1][r]) + (S[2][r] + S[3][r]);
#pragma unroll
    for (int off = 1; off < 16; off <<= 1)
#pragma unroll
      for (int r = 0; r < 4; r++) ps[r] += __shfl_xor(ps[r], off);
#pragma unroll
    for (int r = 0; r < 4; r++) l_[r] = l_[r] * al[r] + ps[r];

    // rescale O
#pragma unroll
    for (int td = 0; td < 4; td++)
#pragma unroll
      for (int r = 0; r < 4; r++) Oacc[td][r] *= al[r];

    // ---- P -> LDS (bf16), wave-private rows; 2-way max bank aliasing
#pragma unroll
    for (int tn = 0; tn < 4; tn++)
#pragma unroll
      for (int r = 0; r < 4; r++)
        Ps[(w * 16 + quad * 4 + r) * 68 + tn * 16 + l15] = f2bf(S[tn][r]);
    asm volatile("s_waitcnt lgkmcnt(0)" ::: "memory");  // within-wave cross-lane

    // ---- O += P V  (A = P rows strip, k=j; B = Vt, d rows, j inner)
#pragma unroll
    for (int ks = 0; ks < 2; ks++) {
      int off = (w * 16 + l15) * 68 + ks * 32 + quad * 8;
      bf16x4 plo = *(const bf16x4*)&Ps[off];
      bf16x4 phi = *(const bf16x4*)&Ps[off + 4];
      bf16x8 ap = __builtin_shufflevector(plo, phi, 0, 1, 2, 3, 4, 5, 6, 7);
      int kc = ks * 4 + quad;
#pragma unroll
      for (int td = 0; td < 4; td++) {
        bf16x8 bv = *(const bf16x8*)&Vs[kc * 512 + (td * 16 + l15) * 8];
        Oacc[td] = __builtin_amdgcn_mfma_f32_16x16x32_bf16(ap, bv, Oacc[td], 0, 0, 0);
      }
    }
  }

  // ---- epilogue: y[(b*T + q)][h*64 + d] bf16, token-major for proj GEMM
  const int b = bh >> 4, h = bh & 15;
  float inv[4];
#pragma unroll
  for (int r = 0; r < 4; r++) inv[r] = 1.0f / l_[r];
#pragma unroll
  for (int td = 0; td < 4; td++)
#pragma unroll
    for (int r = 0; r < 4; r++) {
      int q = q0 + w * 16 + quad * 4 + r;
      y[((size_t)(b * 2048 + q)) * 1024 + h * 64 + td * 16 + l15] =
          __float2bfloat16(Oacc[td][r] * inv[r]);
    }
}

// ---------------------------------------------------------------------------
extern "C" void kernel_launch(void* const* d_in, const int* in_sizes, int n_in,
                              void* d_out, int out_size, void* d_ws, size_t ws_size,
                              hipStream_t stream) {
  const float* x     = (const float*)d_in[0];
  const float* wqkv  = (const float*)d_in[1];
  const float* wproj = (const float*)d_in[2];
  float* out = (float*)d_out;

  char* ws = (char*)d_ws;
  // [0,16M)   xb (dead after QKV gemm) -> reused as Vt
  // [16,22M)  Wqkv bf16   [22,24M) Wproj bf16
  // [24,40M)  Qh   [40,56M) Kh   [56,72M) Vh   [72,88M) y bf16
  unsigned short* xb     = (unsigned short*)(ws);
  unsigned short* vtb    = (unsigned short*)(ws);  // aliases xb (after gemm)
  unsigned short* wqkvb  = (unsigned short*)(ws + (size_t)16 * 1024 * 1024);
  unsigned short* wprojb = (unsigned short*)(ws + (size_t)22 * 1024 * 1024);
  unsigned short* qh     = (unsigned short*)(ws + (size_t)24 * 1024 * 1024);
  unsigned short* kh     = (unsigned short*)(ws + (size_t)40 * 1024 * 1024);
  unsigned short* vh     = (unsigned short*)(ws + (size_t)56 * 1024 * 1024);
  unsigned short* yb     = (unsigned short*)(ws + (size_t)72 * 1024 * 1024);

  const int nx = MM * CC;
  const int nq = 3 * CC * CC;
  const int np = CC * CC;

  f32_to_bf16<<<nx / 1024, 256, 0, stream>>>(x,     (__hip_bfloat16*)xb,     nx);
  f32_to_bf16<<<nq / 1024, 256, 0, stream>>>(wqkv,  (__hip_bfloat16*)wqkvb,  nq);
  f32_to_bf16<<<np / 1024, 256, 0, stream>>>(wproj, (__hip_bfloat16*)wprojb, np);

  // qkv = x @ Wqkv^T, scattered to head-major Q/K/V (Q pre-scaled)
  gemm_bt<1><<<dim3(MM / 128, (3 * CC) / 128), 256, 0, stream>>>(
      xb, wqkvb, nullptr, MM, 3 * CC, CC, qh, kh, vh);

  // V -> chunk-blocked transpose (into xb region, now dead)
  transpose_v<<<dim3(32, 64), 256, 0, stream>>>(vh, vtb);

  // attention
  attn_mfma<<<dim3(TT / 64, BB * HH), 256, 0, stream>>>(
      qh, kh, vtb, (__hip_bfloat16*)yb);

  // out = y @ Wproj^T -> fp32
  gemm_bt<0><<<dim3(MM / 128, CC / 128), 256, 0, stream>>>(
      yb, wprojb, (void*)out, MM, CC, CC, nullptr, nullptr, nullptr);
}